// Round 7
// baseline (112.615 us; speedup 1.0000x reference)
//
#include <hip/hip_runtime.h>

#define NEWL 150
#define EMBD 64
#define NCOL 256
#define CIMU 48
#define CEMG 16

#define KSTI 225            // total 32-wide k-steps imu (150*48/32)
#define KSTE 75             // total k-steps emg
#define NCHI 5              // imu s-chunks (30 s -> 45 ksteps each)

typedef __bf16 bf16x8_t __attribute__((ext_vector_type(8)));
typedef __bf16 bf16x4_t __attribute__((ext_vector_type(4)));
typedef float f32x4_t __attribute__((ext_vector_type(4)));

__device__ __forceinline__ f32x4_t mfma16(bf16x8_t a, bf16x8_t b, f32x4_t c) {
  return __builtin_amdgcn_mfma_f32_16x16x32_bf16(a, b, c, 0, 0, 0);
}

// raw barrier: LDS-ordering only, NO vmcnt drain (prefetches stay in flight)
#define BAR() do {                                          \
    asm volatile("s_waitcnt lgkmcnt(0)" ::: "memory");      \
    __builtin_amdgcn_s_barrier();                           \
    asm volatile("" ::: "memory");                          \
  } while (0)

// ---------- K0: combined weights (both modalities, one w_proj read) + bias partials
// W_pack[cb][ks][lane=h*16+(col&15)][u], k = ks*32 + h*8 + u
template <int C, int KST>
__device__ __forceinline__ void wcomb_body(const float* __restrict__ wemb,
                                           const float* wreg,
                                           __bf16* __restrict__ wpk, int s, int j) {
  const int cb = j >> 4, lr = j & 15;
#pragma unroll
  for (int q = 0; q < C / 8; ++q) {
    const int kq = (s * C) / 8 + q;
    const int ks = kq >> 2, h = kq & 3;
    bf16x8_t tv;
#pragma unroll
    for (int u = 0; u < 8; ++u) {
      const float* we = wemb + (q * 8 + u) * EMBD;
      float acc = 0.f;
#pragma unroll
      for (int e = 0; e < EMBD; ++e) acc = fmaf(we[e], wreg[e], acc);
      tv[u] = (__bf16)acc;
    }
    *(bf16x8_t*)(wpk + (((size_t)cb * KST + ks) * 64 + h * 16 + lr) * 8) = tv;
  }
}

__global__ __launch_bounds__(256) void wcomb_kernel(
    const float* __restrict__ w_emb_imu, const float* __restrict__ w_emb_emg,
    const float* __restrict__ b_emb_imu, const float* __restrict__ b_emb_emg,
    const float* __restrict__ w_proj,
    __bf16* __restrict__ wpk_imu, __bf16* __restrict__ wpk_emg,
    float* __restrict__ bpart) {
  const int s = blockIdx.x, j = threadIdx.x;
  const float* wp_base = w_proj + (size_t)s * EMBD * NCOL + j;
  float wreg[EMBD];
#pragma unroll
  for (int e = 0; e < EMBD; ++e) wreg[e] = wp_base[(size_t)e * NCOL];
  float bi = 0.f, be = 0.f;
#pragma unroll
  for (int e = 0; e < EMBD; ++e) {
    bi = fmaf(b_emb_imu[e], wreg[e], bi);
    be = fmaf(b_emb_emg[e], wreg[e], be);
  }
  bpart[(size_t)s * NCOL + j] = bi;
  bpart[((size_t)NEWL + s) * NCOL + j] = be;
  wcomb_body<CIMU, KSTI>(w_emb_imu, wreg, wpk_imu, s, j);
  wcomb_body<CEMG, KSTE>(w_emb_emg, wreg, wpk_emg, s, j);
}

__global__ __launch_bounds__(256) void bias_kernel(
    const float* __restrict__ b_proj, const float* __restrict__ bpart,
    float* __restrict__ bias) {
  const int m = blockIdx.x, j = threadIdx.x;
  float acc = b_proj[j];
  for (int s = 0; s < NEWL; ++s) acc += bpart[((size_t)m * NEWL + s) * NCOL + j];
  bias[m * NCOL + j] = acc;
}

// ---------- K1: fused ragged-interp + streaming MFMA GEMM
// Block = 16 rows x 256 cols x (s-chunk). Group = SPG s = 3 ksteps.
// Pipeline: gathers issued 2 groups ahead (raw barriers keep them in flight),
// lerp+LDS-write 1 group ahead, B-frags loaded just-in-time from L2.
template <bool IMU>
__device__ __forceinline__ void run_tile(
    __bf16 (*lds)[3][512],
    const float* __restrict__ xsrc, const int* __restrict__ lens,
    const __bf16* __restrict__ wpk, float* __restrict__ Pout,
    const float* __restrict__ bias1, int B, int T, int c, int mt) {
  constexpr int CH  = IMU ? CIMU : CEMG;
  constexpr int KST = IMU ? KSTI : KSTE;
  constexpr int NG  = IMU ? 15 : 25;   // groups
  constexpr int SPG = IMU ? 2 : 6;     // s per group
  constexpr int NT4 = IMU ? 3 : 4;     // float4 gathers per thread

  const int tid = threadIdx.x, wv = tid >> 6, l = tid & 63;

  // produce-side thread mapping
  int b4, sidx, row, qq;
  bool act;
  if (IMU) {  // 16b x 2s x 2row x 4quarter = 256
    act = true;
    b4 = tid >> 4; sidx = (tid >> 3) & 1; row = (tid >> 2) & 1; qq = tid & 3;
  } else {    // 16b x 6s x 2row = 192
    act = tid < 192;
    const int t12 = tid / 12;
    b4 = t12; const int re = tid - t12 * 12; sidx = re >> 1; row = re & 1; qq = 0;
  }
  const int prt = IMU ? (l ^ 4) : (l ^ 1);
  const int b = mt * 16 + (act ? b4 : 0);
  int lenv = 1; float scale = 0.f;
  if (act) { lenv = lens[b]; scale = (float)lenv * (1.0f / 150.0f); }
  const float* xg = xsrc + (size_t)b * T * CH + (IMU ? qq * 12 : 0);
  const int sb = IMU ? c * 30 : 0;

  const __bf16* bg = wpk + (((size_t)(wv * 4) * KST + (IMU ? c * 45 : 0)) * 64 + l) * 8;
  const size_t PL = (size_t)KST * 512;

  float4 gv[2][NT4];
  float wSl[2];
  bf16x8_t bB[12];
  f32x4_t acc[4];
#pragma unroll
  for (int n = 0; n < 4; ++n) acc[n] = (f32x4_t){0.f, 0.f, 0.f, 0.f};

#define ISSUE(g_, S) do { if (act) {                                          \
    const int s_ = sb + (g_) * SPG + sidx;                                    \
    float src_ = fmaxf(((float)s_ + 0.5f) * scale - 0.5f, 0.f);               \
    int i0_ = min((int)src_, lenv - 1);                                       \
    int i1_ = min(i0_ + 1, lenv - 1);                                         \
    wSl[S] = src_ - (float)i0_;                                               \
    const float* p_ = xg + (size_t)(row ? i1_ : i0_) * CH;                    \
    _Pragma("unroll")                                                         \
    for (int t = 0; t < NT4; ++t) gv[S][t] = *(const float4*)(p_ + t * 4);    \
  } } while (0)

#define LERP(S, BUF) do { if (act) {                                          \
    const float w_ = wSl[S], om_ = 1.f - w_;                                  \
    float o_[NT4 * 4];                                                        \
    _Pragma("unroll")                                                         \
    for (int t = 0; t < NT4; ++t) {                                           \
      float4 v_ = gv[S][t];                                                   \
      float px = __shfl(v_.x, prt), py = __shfl(v_.y, prt);                   \
      float pz = __shfl(v_.z, prt), pw = __shfl(v_.w, prt);                   \
      o_[t * 4 + 0] = v_.x * om_ + px * w_;                                   \
      o_[t * 4 + 1] = v_.y * om_ + py * w_;                                   \
      o_[t * 4 + 2] = v_.z * om_ + pz * w_;                                   \
      o_[t * 4 + 3] = v_.w * om_ + pw * w_;                                   \
    }                                                                         \
    if (row == 0) {                                                           \
      if (IMU) {                                                              \
        _Pragma("unroll")                                                     \
        for (int t2 = 0; t2 < 3; ++t2) {                                      \
          bf16x4_t ob;                                                        \
          _Pragma("unroll")                                                   \
          for (int u = 0; u < 4; ++u) ob[u] = (__bf16)o_[t2 * 4 + u];         \
          const int k_ = sidx * 48 + qq * 12 + t2 * 4;                        \
          const int kq_ = k_ >> 3, u_ = k_ & 7;                               \
          *(bf16x4_t*)(&lds[BUF][kq_ >> 2][((kq_ & 3) * 16 + b4) * 8 + u_]) = ob; \
        }                                                                     \
      } else {                                                                \
        _Pragma("unroll")                                                     \
        for (int t2 = 0; t2 < 2; ++t2) {                                      \
          bf16x8_t ob;                                                        \
          _Pragma("unroll")                                                   \
          for (int u = 0; u < 8; ++u) ob[u] = (__bf16)o_[t2 * 8 + u];         \
          const int kq_ = sidx * 2 + t2;                                      \
          *(bf16x8_t*)(&lds[BUF][kq_ >> 2][((kq_ & 3) * 16 + b4) * 8]) = ob;  \
        }                                                                     \
      }                                                                       \
    }                                                                         \
  } } while (0)

#define LOADB(g_) do {                                                        \
    _Pragma("unroll")                                                         \
    for (int ks = 0; ks < 3; ++ks)                                            \
      _Pragma("unroll")                                                       \
      for (int n = 0; n < 4; ++n)                                             \
        bB[ks * 4 + n] = *(const bf16x8_t*)(bg + (size_t)n * PL +             \
                                            (size_t)((g_) * 3 + ks) * 512);   \
  } while (0)

#define COMP(BUF) do {                                                        \
    _Pragma("unroll")                                                         \
    for (int ks = 0; ks < 3; ++ks) {                                          \
      bf16x8_t a_ = *(const bf16x8_t*)(&lds[BUF][ks][l * 8]);                 \
      acc[0] = mfma16(a_, bB[ks * 4 + 0], acc[0]);                            \
      acc[1] = mfma16(a_, bB[ks * 4 + 1], acc[1]);                            \
      acc[2] = mfma16(a_, bB[ks * 4 + 2], acc[2]);                            \
      acc[3] = mfma16(a_, bB[ks * 4 + 3], acc[3]);                            \
    }                                                                         \
  } while (0)

  // prologue
  ISSUE(0, 0);
  ISSUE(1, 1);
  LERP(0, 0);
  BAR();

  for (int gp = 0; gp < (NG + 1) / 2; ++gp) {
    const int g0 = gp * 2;
    {
      LOADB(g0);
      if (g0 + 2 < NG) ISSUE(g0 + 2, 0);
      COMP(0);
      if (g0 + 1 < NG) LERP(1, 1);
      BAR();
    }
    const int g1 = g0 + 1;
    if (g1 < NG) {
      LOADB(g1);
      if (g1 + 2 < NG) ISSUE(g1 + 2, 1);
      COMP(1);
      if (g1 + 1 < NG) LERP(0, 0);
      BAR();
    }
  }

  // epilogue: C/D col = lane&15, row = (lane>>4)*4 + reg
  const int lh = l >> 4, lr = l & 15;
  float* Pb = Pout + (size_t)(mt * 16 + lh * 4) * NCOL + wv * 64 + lr;
#pragma unroll
  for (int n = 0; n < 4; ++n) {
    const float badd = IMU ? 0.f : bias1[wv * 64 + n * 16 + lr];
#pragma unroll
    for (int jj = 0; jj < 4; ++jj)
      Pb[(size_t)jj * NCOL + n * 16] = acc[n][jj] + badd;
  }
#undef ISSUE
#undef LERP
#undef LOADB
#undef COMP
}

__global__ __launch_bounds__(256, 3) void fused_kernel(
    const float* __restrict__ x_imu, const float* __restrict__ x_emg,
    const int* __restrict__ lens,
    const __bf16* __restrict__ wpk_imu, const __bf16* __restrict__ wpk_emg,
    const float* __restrict__ bias, float* __restrict__ p_imu,
    float* __restrict__ out, int B, int T) {
  __shared__ __bf16 lds[2][3][512];
  const int span = B >> 4;  // 128
  const int bid = blockIdx.x;
  if (bid < NCHI * span) {
    const int c = bid / span, mt = bid - c * span;
    run_tile<true>(lds, x_imu, lens, wpk_imu, p_imu + (size_t)c * B * NCOL,
                   nullptr, B, T, c, mt);
  } else {
    const int mt = bid - NCHI * span;
    run_tile<false>(lds, x_emg, lens, wpk_emg, out + (size_t)B * NCOL,
                    bias + NCOL, B, T, 0, mt);
  }
}

// ---------- K2: imu split-K combine + bias -> d_out[0..B*256)
__global__ __launch_bounds__(256) void combine_kernel(
    const float* __restrict__ bias, const float* __restrict__ p_imu,
    float* __restrict__ out, int B) {
  const int b = blockIdx.x, j = threadIdx.x;
  const size_t n = (size_t)B * NCOL;
  const size_t o = (size_t)b * NCOL + j;
  float v = bias[j];
#pragma unroll
  for (int c = 0; c < NCHI; ++c) v += p_imu[c * n + o];
  out[o] = v;
}

extern "C" void kernel_launch(void* const* d_in, const int* in_sizes, int n_in,
                              void* d_out, int out_size, void* d_ws, size_t ws_size,
                              hipStream_t stream) {
  const float* x_imu     = (const float*)d_in[0];
  const float* x_emg     = (const float*)d_in[1];
  const int*   lens      = (const int*)d_in[2];
  const float* w_emb_imu = (const float*)d_in[3];
  const float* b_emb_imu = (const float*)d_in[4];
  const float* w_emb_emg = (const float*)d_in[5];
  const float* b_emb_emg = (const float*)d_in[6];
  const float* w_proj    = (const float*)d_in[7];
  const float* b_proj    = (const float*)d_in[8];
  float* out = (float*)d_out;

  const int B = in_sizes[2];
  const int T = in_sizes[0] / (B * CIMU);

  char* ws = (char*)d_ws;
  __bf16* wpk_imu = (__bf16*)ws;  ws += (size_t)NCOL * KSTI * 32 * 2;  // 3.69 MB
  __bf16* wpk_emg = (__bf16*)ws;  ws += (size_t)NCOL * KSTE * 32 * 2;  // 1.23 MB
  float*  bias    = (float*)ws;   ws += 2 * NCOL * 4;
  float*  bpart   = (float*)ws;   ws += (size_t)2 * NEWL * NCOL * 4;
  float*  p_imu   = (float*)ws;   ws += (size_t)NCHI * B * NCOL * 4;   // 10.5 MB

  wcomb_kernel<<<NEWL, 256, 0, stream>>>(w_emb_imu, w_emb_emg, b_emb_imu,
                                         b_emb_emg, w_proj, wpk_imu, wpk_emg,
                                         bpart);
  bias_kernel<<<2, 256, 0, stream>>>(b_proj, bpart, bias);
  const int nblk = (NCHI + 1) * (B >> 4);  // 768
  fused_kernel<<<nblk, 256, 0, stream>>>(x_imu, x_emg, lens, wpk_imu, wpk_emg,
                                         bias, p_imu, out, B, T);
  combine_kernel<<<B, 256, 0, stream>>>(bias, p_imu, out, B);
}